// Round 2
// baseline (165.916 us; speedup 1.0000x reference)
//
#include <hip/hip_runtime.h>

// PatchMatch brute-force NN on MI355X.
// s,t (4,16,64,64) fp32; descriptor = 3x3 replicate-padded patch, K=144.
// d2(i,j) = qn_i - 2*cross(i,j) + pn_j; argmin_j (ties -> smallest j).
// Outputs (flat, ALL FLOAT32): nnf (4,2,64,64) then nnd (4,1,64,64).
//
// R14 vs R13 (total 125us; mfma 63.3us @ MfmaUtil 38% / Occupancy 19%):
// R13 proved the kernel is occupancy/latency-bound (removing 25% MFMA work,
// all LDS conflicts and fmafs moved time by 2.5%). R14 raises residency
// 2 -> 3 blocks/CU (8 -> 12 waves/CU):
//  - LDS 61.4KB -> 51.2KB/block: KKSTRIDE 528->512 (conflict-free without
//    pad now), and K-chunk 8 (kk16,17) is loaded per-phase from L2 into
//    registers instead of being DMA-staged (2 f16x8 loads, ~800cyc slack).
//  - grid 512 -> 1024 (SPLITS_M 8, 16 phases/block, j-split 512);
//    split=bid&7 pins each split's 1.2MB B panel to one XCD's L2.
//  - uniform staging {4,4,4,4} kk-rows/wave, uniform s_waitcnt vmcnt(4).
//  - descriptor stride 20 -> 18 kk rows (ws ~20MB, was ~21.5MB).
//  - __launch_bounds__(256,3) to hold 3 waves/SIMD.

#define N_  4
#define C_  16
#define H_  64
#define W_  64
#define HW_ 4096
#define KK_ 18               // kk blocks of 8 (K=144)
#define SPLITS_M 8           // j-splits; 512 j per split, 16 tiles of 32
#define KKSTRIDE 512         // f16 per kk block in LDS: 32 hi + 32 lo cols x8

#define SPLITS_V 4           // fallback j-splits
#define TILES_PER_SPLIT_V 4

typedef _Float16 f16;
typedef _Float16 f16x8 __attribute__((ext_vector_type(8)));
typedef float    f32x4 __attribute__((ext_vector_type(4)));
typedef float    f32x16 __attribute__((ext_vector_type(16)));

__device__ __forceinline__ int iclamp(int v, int lo, int hi) {
    return v < lo ? lo : (v > hi ? hi : v);
}

__device__ __forceinline__ void async_ld16(const void* g, void* l) {
    __builtin_amdgcn_global_load_lds(
        (const __attribute__((address_space(1))) unsigned int*)g,
        (__attribute__((address_space(3))) unsigned int*)l, 16, 0, 0);
}

// ---------------------------------------------------------------------------
// Kernel 1: K-major fp16 hi/lo descriptors + squared norms.
// D[(n*18 + kk)*4096 + pix][8], kk = k/8, k = d*16 + c (d = dy*3+dx).
// One block per image row; wave q handles kk = q*5..q*5+4 for all 64 px ->
// every store is a 1KB coalesced wavefront store. grid (64, N_, 2).
// ---------------------------------------------------------------------------
__global__ __launch_bounds__(256)
void build_desc_norms_kernel(const float* __restrict__ s,
                             const float* __restrict__ t,
                             f16* __restrict__ Qh, f16* __restrict__ Ql,
                             f16* __restrict__ Ph, f16* __restrict__ Pl,
                             float* __restrict__ pn,
                             float* __restrict__ qn) {
    const int y0  = blockIdx.x;                 // image row
    const int n   = blockIdx.y;
    const int src = blockIdx.z;                 // 0: t, 1: s
    const float* img = (src ? s : t) + n * (C_ * HW_);
    f16* Dh = src ? Qh : Ph;
    f16* Dl = src ? Ql : Pl;
    float* nrm = src ? qn : pn;

    __shared__ float imgS[3][C_][W_];           // 12 KB: rows y0-1..y0+1
    __shared__ float nS[4][W_];
    const int tid = threadIdx.x;
    #pragma unroll
    for (int k = 0; k < 12; ++k) {
        const int idx = tid + k * 256;          // 0..3071
        const int x = idx & 63, c = (idx >> 6) & 15, r = idx >> 10;  // r 0..2
        const int gy = iclamp(y0 + r - 1, 0, H_ - 1);
        imgS[r][c][x] = img[c * HW_ + gy * W_ + x];
    }
    __syncthreads();

    const int q = tid >> 6, x = tid & 63;       // wave, lane(=pixel x)
    const int pix = y0 * W_ + x;
    float nacc = 0.f;
    #pragma unroll
    for (int u = 0; u < 5; ++u) {
        const int kk = q * 5 + u;               // 0..19
        if (kk < KK_) {
            f16x8 hv, lv;
            const int d  = kk >> 1;             // 0..8
            const int c0 = (kk & 1) * 8;
            const int dy = (d * 11) >> 5;       // d/3 for d in [0,8]
            const int dx = d - dy * 3;
            const int xs = iclamp(x + dx - 1, 0, W_ - 1);
            #pragma unroll
            for (int cc = 0; cc < 8; ++cc) {
                const float v = imgS[dy][c0 + cc][xs];
                const f16 h = (f16)v;
                hv[cc] = h;
                lv[cc] = (f16)(v - (float)h);
                nacc += v * v;
            }
            const size_t off = ((size_t)(n * KK_ + kk) * HW_ + pix) * 8;
            *(f16x8*)&Dh[off] = hv;             // 64 lanes x 16B contiguous
            *(f16x8*)&Dl[off] = lv;
        }
    }
    nS[q][x] = nacc;
    __syncthreads();
    if (tid < W_)
        nrm[n * HW_ + pix] = nS[0][tid] + nS[1][tid] + nS[2][tid] + nS[3][tid];
}

// ---------------------------------------------------------------------------
// Kernel 2: MFMA GEMM + fused argmax. 1D grid 1024 blocks (split=bid&7 ->
// one split per XCD); block = 4 waves, wave = one 32-row output stripe.
// j: 32-wide tiles x16/split, TRIPLE-buffered async DMA staging of K-chunks
// 0..7 (kk 0..15); K-chunk 8 (kk 16,17) loaded per-phase from L2 into regs.
// Raw s_waitcnt vmcnt(4)+s_barrier per tile (prefetch in flight across it).
// LDS per buffer: [kk 0..15][h(32 cols)|l(32 cols)][8 f16], KKSTRIDE=512.
// mfma_f32_32x32x16_f16: A/B [idx=lane&31][k=(lane>>5)*8+e];
// C col=lane&31, row=(reg&3)+8*(reg>>2)+4*(lane>>5).
// Cf initialized to -pn_j/2: argmin d2 == argmax Cf; partial stores -2*Cf.
// ---------------------------------------------------------------------------
__global__ __launch_bounds__(256, 3)
void mfma_nn_kernel(const f16* __restrict__ Qh, const f16* __restrict__ Ql,
                    const f16* __restrict__ Ph, const f16* __restrict__ Pl,
                    const float* __restrict__ pn_g,
                    unsigned long long* __restrict__ partial) {
    const int bid   = blockIdx.x;
    const int split = bid & 7;          // fixed XCD under round-robin
    const int n     = (bid >> 3) & 3;
    const int iblk  = bid >> 5;         // 0..31
    const int tid  = threadIdx.x;
    const int wave = tid >> 6, lane = tid & 63;
    const int col  = lane & 31;         // A row / B col / C col
    const int half = lane >> 5;         // k-half within a 16-chunk
    const int irow0 = iblk * 128 + wave * 32;

    __shared__ f16 B0[16 * KKSTRIDE];   // 16384 B each
    __shared__ f16 B1[16 * KKSTRIDE];
    __shared__ f16 B2[16 * KKSTRIDE];
    __shared__ float pnS[512];          // this split's pn

    // ---- A fragments, resident (72 VGPR): 9 chunks of K=16 ----
    f16x8 Ah[9], Al[9];
    #pragma unroll
    for (int c = 0; c < 9; ++c) {
        const size_t off = ((size_t)(n * KK_ + 2 * c + half) * HW_ +
                            irow0 + col) * 8;
        Ah[c] = *(const f16x8*)(Qh + off);
        Al[c] = *(const f16x8*)(Ql + off);
    }

    const int jsplit0 = split * 512;
    pnS[tid]       = pn_g[n * HW_ + jsplit0 + tid];
    pnS[tid + 256] = pn_g[n * HW_ + jsplit0 + tid + 256];

    // per-lane base for the register-loaded K-chunk 8 (kk 16+half)
    const f16* p8h = Ph + ((size_t)(n * KK_ + 16 + half) * HW_ + jsplit0) * 8;
    const f16* p8l = Pl + ((size_t)(n * KK_ + 16 + half) * HW_ + jsplit0) * 8;

    float    bd[16];
    unsigned bj[16];
    #pragma unroll
    for (int r = 0; r < 16; ++r) { bd[r] = -3.0e38f; bj[r] = 0u; }

    // staging: 16 kk rows, 4 per wave (uniform)
    const int kk0 = wave * 4;
    const f16* sbase = half ? Pl : Ph;  // lanes 0-31: hi rows, 32-63: lo rows

    #define STAGE(BUF, T)                                                     \
        {   _Pragma("unroll")                                                 \
            for (int u = 0; u < 4; ++u) {                                     \
                const int kk = kk0 + u;                                       \
                const f16* g = sbase + ((size_t)(n * KK_ + kk) * HW_ +        \
                                        jsplit0 + (T) * 32 + col) * 8;        \
                async_ld16(g, (void*)&BUF[kk * KKSTRIDE + lane * 8]);         \
            }                                                                 \
        }

    // One pipeline phase: wait(WN)+barrier, issue chunk-8 reg loads (before
    // the DMA so the compiler's wait for them leaves the new stage in
    // flight), stage tile ST into SBUF, compute tile CT from CBUF.
    #define PHASE(WN, SBUF, ST, DOST, CBUF, CT)                               \
        {   asm volatile("s_waitcnt vmcnt(" #WN ")" ::: "memory");            \
            asm volatile("s_barrier" ::: "memory");                           \
            const int j8 = (CT) * 32 + col;                                   \
            const f16x8 b8h = *(const f16x8*)(p8h + (size_t)j8 * 8);          \
            const f16x8 b8l = *(const f16x8*)(p8l + (size_t)j8 * 8);          \
            if (DOST) STAGE(SBUF, ST);                                        \
            const float pnv = -0.5f * pnS[j8];                                \
            f32x16 Cf;                                                        \
            _Pragma("unroll")                                                 \
            for (int r = 0; r < 16; ++r) Cf[r] = pnv;                         \
            __builtin_amdgcn_s_setprio(1);                                    \
            _Pragma("unroll")                                                 \
            for (int c = 0; c < 8; ++c) {                                     \
                const int kb = (2 * c + half) * KKSTRIDE + col * 8;           \
                const f16x8 bh = *(const f16x8*)&CBUF[kb];                    \
                const f16x8 bl = *(const f16x8*)&CBUF[kb + 256];              \
                Cf = __builtin_amdgcn_mfma_f32_32x32x16_f16(                  \
                    Ah[c], bh, Cf, 0, 0, 0);                                  \
                Cf = __builtin_amdgcn_mfma_f32_32x32x16_f16(                  \
                    Al[c], bh, Cf, 0, 0, 0);                                  \
                Cf = __builtin_amdgcn_mfma_f32_32x32x16_f16(                  \
                    Ah[c], bl, Cf, 0, 0, 0);                                  \
            }                                                                 \
            Cf = __builtin_amdgcn_mfma_f32_32x32x16_f16(                      \
                Ah[8], b8h, Cf, 0, 0, 0);                                     \
            Cf = __builtin_amdgcn_mfma_f32_32x32x16_f16(                      \
                Al[8], b8h, Cf, 0, 0, 0);                                     \
            Cf = __builtin_amdgcn_mfma_f32_32x32x16_f16(                      \
                Ah[8], b8l, Cf, 0, 0, 0);                                     \
            __builtin_amdgcn_s_setprio(0);                                    \
            _Pragma("unroll")                                                 \
            for (int r = 0; r < 16; ++r)                                      \
                if (Cf[r] > bd[r]) { bd[r] = Cf[r]; bj[r] = (unsigned)j8; }   \
        }

    STAGE(B0, 0)
    STAGE(B1, 1)
    __syncthreads();    // pnS + first two stages visible (one-time drain)

    for (int g = 0; g < 4; ++g) {       // tiles 0..11, stages 2..13
        const int t = g * 3;
        PHASE(4, B2, t + 2, true,  B0, t)
        PHASE(4, B0, t + 3, true,  B1, t + 1)
        PHASE(4, B1, t + 4, true,  B2, t + 2)
    }
    PHASE(4, B2, 14, true,  B0, 12)
    PHASE(4, B0, 15, true,  B1, 13)
    PHASE(4, B1, 0,  false, B2, 14)
    PHASE(0, B0, 0,  false, B0, 15)
    #undef STAGE
    #undef PHASE

    // ---- argmax reduce across the 32 cols (lanes col=0..31 per half) ----
    #pragma unroll
    for (int r = 0; r < 16; ++r) {
        float    d = bd[r];
        unsigned j = (unsigned)jsplit0 + bj[r];
        #pragma unroll
        for (int off = 1; off < 32; off <<= 1) {
            const float    od = __shfl_xor(d, off, 64);
            const unsigned oj = __shfl_xor(j, off, 64);
            const bool take = (od > d) || (od == d && oj < j);
            d = take ? od : d;
            j = take ? oj : j;
        }
        if (col == 0) {
            const int i = irow0 + (r & 3) + 8 * (r >> 2) + 4 * half;
            partial[(size_t)(split * N_ + n) * HW_ + i] =
                ((unsigned long long)j << 32) |
                (unsigned long long)__float_as_uint(-2.f * d);
        }
    }
}

// ---------------------------------------------------------------------------
// Kernel 3: reduce splits, add qn, decode, write outputs (float32)
// ---------------------------------------------------------------------------
__global__ __launch_bounds__(256)
void finalize_mfma_kernel(const unsigned long long* __restrict__ partial,
                          const float* __restrict__ qn_g,
                          float* __restrict__ out) {
    const int id  = blockIdx.x * 256 + threadIdx.x;   // 0..16383
    const int n   = id >> 12;
    const int pix = id & 4095;
    float    bd = 3.0e38f;
    unsigned bj = 0u;
    #pragma unroll
    for (int sp = 0; sp < SPLITS_M; ++sp) {
        const unsigned long long v = partial[(size_t)(sp * N_ + n) * HW_ + pix];
        const float    d = __uint_as_float((unsigned)(v & 0xffffffffull));
        const unsigned j = (unsigned)(v >> 32);
        const bool take = (d < bd) || (d == bd && j < bj);
        bd = take ? d : bd;
        bj = take ? j : bj;
    }
    out[n * 2 * HW_ + pix]            = (float)(bj >> 6);          // idy
    out[n * 2 * HW_ + HW_ + pix]      = (float)(bj & 63);          // idx_x
    out[N_ * 2 * HW_ + n * HW_ + pix] = bd + qn_g[n * HW_ + pix];  // nnd
}

// ===========================================================================
// Fallback path (fp32 vector) + helpers — unchanged
// ===========================================================================
__global__ __launch_bounds__(256)
void prep_norms_kernel(const float* __restrict__ s,
                       const float* __restrict__ t,
                       float* __restrict__ pn,
                       float* __restrict__ qn) {
    const int gid   = blockIdx.x * 256 + threadIdx.x;
    const int which = gid >> 14;
    const int id    = gid & 16383;
    const int n     = id >> 12;
    const int pix   = id & 4095;
    const int y = pix >> 6, x = pix & 63;
    const float* base = (which ? s : t) + n * (C_ * HW_);
    float acc = 0.f;
    for (int c = 0; c < C_; ++c) {
        const float* bc = base + c * HW_;
        #pragma unroll
        for (int dy = 0; dy < 3; ++dy) {
            const float* br = bc + iclamp(y + dy - 1, 0, H_ - 1) * W_;
            #pragma unroll
            for (int dx = 0; dx < 3; ++dx) {
                float v = br[iclamp(x + dx - 1, 0, W_ - 1)];
                acc += v * v;
            }
        }
    }
    (which ? qn : pn)[id] = acc;
}

__global__ __launch_bounds__(256)
void patchmatch_main_kernel(const float* __restrict__ s,
                            const float* __restrict__ t,
                            const float* __restrict__ pn_g,
                            const float* __restrict__ qn_g,
                            unsigned long long* __restrict__ partial) {
    const int yq    = blockIdx.x;
    const int n     = blockIdx.y;
    const int split = blockIdx.z;
    const int tid  = threadIdx.x;
    const int tx   = tid & 15;
    const int ty   = tid >> 4;
    const int i0   = ty * 4;
    const int jrow = tx >> 2;
    const int jx0  = (tx & 3) * 16;

    __shared__ float qS[C_][3][68];
    __shared__ float tS[C_][6][68];
    __shared__ float qnS[W_];

    const float* sb = s + n * (C_ * HW_);
    const float* tb = t + n * (C_ * HW_);

    #pragma unroll
    for (int k = 0; k < 3; ++k) {
        const int id = tid + k * 256;
        const int sg = id & 15;
        const int c  = (id >> 4) & 15;
        const int r  = id >> 8;
        const int gr = iclamp(yq + r - 1, 0, H_ - 1);
        const float4 v = *(const float4*)&sb[c * HW_ + gr * W_ + sg * 4];
        float* dst = &qS[c][r][1 + sg * 4];
        dst[0] = v.x; dst[1] = v.y; dst[2] = v.z; dst[3] = v.w;
    }
    if (tid < 48) {
        const int c  = tid & 15;
        const int r  = tid >> 4;
        const int gr = iclamp(yq + r - 1, 0, H_ - 1);
        qS[c][r][0]  = sb[c * HW_ + gr * W_];
        qS[c][r][65] = sb[c * HW_ + gr * W_ + 63];
    }
    if (tid < W_) qnS[tid] = qn_g[n * HW_ + yq * W_ + tid];

    unsigned long long best[4] = {~0ull, ~0ull, ~0ull, ~0ull};

    for (int ytl = 0; ytl < TILES_PER_SPLIT_V; ++ytl) {
        const int yt = split * TILES_PER_SPLIT_V + ytl;
        __syncthreads();
        #pragma unroll
        for (int k = 0; k < 6; ++k) {
            const int id = tid + k * 256;
            const int sg = id & 15;
            const int c  = (id >> 4) & 15;
            const int r  = id >> 8;
            const int gr = iclamp(4 * yt + r - 1, 0, H_ - 1);
            const float4 v = *(const float4*)&tb[c * HW_ + gr * W_ + sg * 4];
            float* dst = &tS[c][r][1 + sg * 4];
            dst[0] = v.x; dst[1] = v.y; dst[2] = v.z; dst[3] = v.w;
        }
        if (tid < 96) {
            const int c  = tid & 15;
            const int r  = tid >> 4;
            const int gr = iclamp(4 * yt + r - 1, 0, H_ - 1);
            tS[c][r][0]  = tb[c * HW_ + gr * W_];
            tS[c][r][65] = tb[c * HW_ + gr * W_ + 63];
        }
        __syncthreads();

        float acc[4][16];
        #pragma unroll
        for (int a = 0; a < 4; ++a)
            #pragma unroll
            for (int b = 0; b < 16; ++b) acc[a][b] = 0.f;

        for (int c = 0; c < C_; ++c) {
            #pragma unroll
            for (int dy = 0; dy < 3; ++dy) {
                float qv[6], tv[18];
                *(float4*)&qv[0] = *(const float4*)&qS[c][dy][i0];
                *(float2*)&qv[4] = *(const float2*)&qS[c][dy][i0 + 4];
                const float* trow = &tS[c][jrow + dy][jx0];
                *(float4*)&tv[0]  = *(const float4*)&trow[0];
                *(float4*)&tv[4]  = *(const float4*)&trow[4];
                *(float4*)&tv[8]  = *(const float4*)&trow[8];
                *(float4*)&tv[12] = *(const float4*)&trow[12];
                *(float2*)&tv[16] = *(const float2*)&trow[16];
                #pragma unroll
                for (int dx = 0; dx < 3; ++dx)
                    #pragma unroll
                    for (int a = 0; a < 4; ++a)
                        #pragma unroll
                        for (int b = 0; b < 16; ++b)
                            acc[a][b] += qv[a + dx] * tv[b + dx];
            }
        }

        const int jbase = yt * 256 + jrow * W_ + jx0;
        float pnv[16];
        const float* png = &pn_g[n * HW_ + jbase];
        *(float4*)&pnv[0]  = *(const float4*)&png[0];
        *(float4*)&pnv[4]  = *(const float4*)&png[4];
        *(float4*)&pnv[8]  = *(const float4*)&png[8];
        *(float4*)&pnv[12] = *(const float4*)&png[12];
        #pragma unroll
        for (int a = 0; a < 4; ++a) {
            const float qn = qnS[i0 + a];
            #pragma unroll
            for (int b = 0; b < 16; ++b) {
                const float d2 = qn + pnv[b] - 2.f * acc[a][b];
                unsigned long long cand =
                    ((unsigned long long)__float_as_uint(d2) << 32) |
                    (unsigned)(jbase + b);
                best[a] = cand < best[a] ? cand : best[a];
            }
        }
    }

    #pragma unroll
    for (int a = 0; a < 4; ++a) {
        unsigned long long v = best[a];
        #pragma unroll
        for (int mm = 8; mm >= 1; mm >>= 1) {
            unsigned long long o = __shfl_xor(v, mm, 64);
            v = o < v ? o : v;
        }
        best[a] = v;
    }
    if (tx == 0) {
        #pragma unroll
        for (int a = 0; a < 4; ++a)
            partial[((split * N_ + n) * HW_) + yq * W_ + i0 + a] = best[a];
    }
}

__global__ __launch_bounds__(256)
void finalize_kernel(const unsigned long long* __restrict__ partial,
                     float* __restrict__ out) {
    const int id  = blockIdx.x * 256 + threadIdx.x;
    const int n   = id >> 12;
    const int pix = id & 4095;
    unsigned long long best = ~0ull;
    #pragma unroll
    for (int sp = 0; sp < SPLITS_V; ++sp) {
        unsigned long long v = partial[(sp * N_ + n) * HW_ + pix];
        best = v < best ? v : best;
    }
    const unsigned j = (unsigned)(best & 0xffffffffu);
    const float d2 = __uint_as_float((unsigned)(best >> 32));
    out[n * 2 * HW_ + pix]            = (float)(j >> 6);
    out[n * 2 * HW_ + HW_ + pix]      = (float)(j & 63);
    out[N_ * 2 * HW_ + n * HW_ + pix] = d2;
}

__global__ __launch_bounds__(256)
void patchmatch_mono_kernel(const float* __restrict__ s,
                            const float* __restrict__ t,
                            float* __restrict__ out) {
    const int yq  = blockIdx.x;
    const int n   = blockIdx.y;
    const int tid = threadIdx.x;
    const int tx  = tid & 15;
    const int ty  = tid >> 4;
    const int i0  = ty * 4;
    const int jrow = tx >> 3;
    const int jx0  = (tx & 7) * 8;

    __shared__ float qS[C_][3][68];
    __shared__ float tS[C_][4][68];
    __shared__ float pnS[HW_];
    __shared__ float qnS[W_];

    const float* sb = s + n * (C_ * HW_);
    const float* tb = t + n * (C_ * HW_);

    for (int jj = tid; jj < HW_; jj += 256) {
        const int y = jj >> 6, x = jj & 63;
        float acc = 0.f;
        for (int c = 0; c < C_; ++c) {
            const float* tc = tb + c * HW_;
            #pragma unroll
            for (int dy = 0; dy < 3; ++dy) {
                const float* tr = tc + iclamp(y + dy - 1, 0, H_ - 1) * W_;
                #pragma unroll
                for (int dx = 0; dx < 3; ++dx) {
                    float v = tr[iclamp(x + dx - 1, 0, W_ - 1)];
                    acc += v * v;
                }
            }
        }
        pnS[jj] = acc;
    }
    for (int idx = tid; idx < C_ * 3 * 66; idx += 256) {
        const int c   = idx / (3 * 66);
        const int rem = idx - c * (3 * 66);
        const int rr  = rem / 66;
        const int xi  = rem - rr * 66;
        qS[c][rr][xi] = sb[c * HW_ + iclamp(yq + rr - 1, 0, H_ - 1) * W_ +
                           iclamp(xi - 1, 0, W_ - 1)];
    }
    __syncthreads();
    if (tid < W_) {
        float acc = 0.f;
        for (int c = 0; c < C_; ++c)
            #pragma unroll
            for (int dy = 0; dy < 3; ++dy)
                #pragma unroll
                for (int dx = 0; dx < 3; ++dx) {
                    float v = qS[c][dy][tid + dx];
                    acc += v * v;
                }
        qnS[tid] = acc;
    }

    unsigned long long best[4] = {~0ull, ~0ull, ~0ull, ~0ull};
    for (int yt = 0; yt < 32; ++yt) {
        __syncthreads();
        for (int idx = tid; idx < C_ * 4 * 66; idx += 256) {
            const int c   = idx / (4 * 66);
            const int rem = idx - c * (4 * 66);
            const int rr  = rem / 66;
            const int xi  = rem - rr * 66;
            tS[c][rr][xi] = tb[c * HW_ + iclamp(2 * yt + rr - 1, 0, H_ - 1) * W_ +
                               iclamp(xi - 1, 0, W_ - 1)];
        }
        __syncthreads();

        float acc[4][8];
        #pragma unroll
        for (int a = 0; a < 4; ++a)
            #pragma unroll
            for (int b = 0; b < 8; ++b) acc[a][b] = 0.f;

        for (int c = 0; c < C_; ++c) {
            #pragma unroll
            for (int dy = 0; dy < 3; ++dy) {
                float qv[8], tv[12];
                *(float4*)&qv[0] = *(const float4*)&qS[c][dy][i0];
                *(float4*)&qv[4] = *(const float4*)&qS[c][dy][i0 + 4];
                const float* trow = &tS[c][jrow + dy][jx0];
                *(float4*)&tv[0] = *(const float4*)&trow[0];
                *(float4*)&tv[4] = *(const float4*)&trow[4];
                *(float4*)&tv[8] = *(const float4*)&trow[8];
                #pragma unroll
                for (int dx = 0; dx < 3; ++dx)
                    #pragma unroll
                    for (int a = 0; a < 4; ++a)
                        #pragma unroll
                        for (int b = 0; b < 8; ++b)
                            acc[a][b] += qv[a + dx] * tv[b + dx];
            }
        }
        const int rbase = (2 * yt + jrow) * W_ + jx0;
        #pragma unroll
        for (int a = 0; a < 4; ++a) {
            const float qn = qnS[i0 + a];
            #pragma unroll
            for (int b = 0; b < 8; ++b) {
                const int j = rbase + b;
                const float d2 = qn + pnS[j] - 2.f * acc[a][b];
                unsigned long long cand =
                    ((unsigned long long)__float_as_uint(d2) << 32) | (unsigned)j;
                best[a] = cand < best[a] ? cand : best[a];
            }
        }
    }
    #pragma unroll
    for (int a = 0; a < 4; ++a) {
        unsigned long long v = best[a];
        #pragma unroll
        for (int mm = 8; mm >= 1; mm >>= 1) {
            unsigned long long o = __shfl_xor(v, mm, 64);
            v = o < v ? o : v;
        }
        best[a] = v;
    }
    if (tx == 0) {
        #pragma unroll
        for (int a = 0; a < 4; ++a) {
            const int x = i0 + a;
            const unsigned j = (unsigned)(best[a] & 0xffffffffu);
            const float d2 = __uint_as_float((unsigned)(best[a] >> 32));
            const int pix = yq * W_ + x;
            out[n * 2 * HW_ + pix]            = (float)(j >> 6);
            out[n * 2 * HW_ + HW_ + pix]      = (float)(j & 63);
            out[N_ * 2 * HW_ + n * HW_ + pix] = d2;
        }
    }
}

// ===========================================================================
extern "C" void kernel_launch(void* const* d_in, const int* in_sizes, int n_in,
                              void* d_out, int out_size, void* d_ws, size_t ws_size,
                              hipStream_t stream) {
    const float* s = (const float*)d_in[0];
    const float* t = (const float*)d_in[1];
    float* out = (float*)d_out;

    // MFMA ws layout:
    //   pn [4][4096] f32 | qn [4][4096] f32 | partial [8][4][4096] u64 |
    //   Qh | Ql | Ph | Pl   each K-major [4][18][4096][8] f16 (4.72 MB)
    const size_t norm_b  = (size_t)N_ * HW_ * 4;
    const size_t part_b  = (size_t)SPLITS_M * N_ * HW_ * 8;
    const size_t desc_b  = (size_t)N_ * HW_ * KK_ * 8 * 2;
    const size_t need_m  = 2 * norm_b + part_b + 4 * desc_b;     // ~20.1 MB

    if (ws_size >= need_m) {
        char* w = (char*)d_ws;
        float* pn = (float*)w;                       w += norm_b;
        float* qn = (float*)w;                       w += norm_b;
        unsigned long long* partial = (unsigned long long*)w; w += part_b;
        f16* Qh = (f16*)w;  w += desc_b;
        f16* Ql = (f16*)w;  w += desc_b;
        f16* Ph = (f16*)w;  w += desc_b;
        f16* Pl = (f16*)w;

        build_desc_norms_kernel<<<dim3(64, N_, 2), 256, 0, stream>>>(
            s, t, Qh, Ql, Ph, Pl, pn, qn);
        mfma_nn_kernel<<<1024, 256, 0, stream>>>(Qh, Ql, Ph, Pl, pn, partial);
        finalize_mfma_kernel<<<64, 256, 0, stream>>>(partial, qn, out);
        return;
    }

    // Fallback: fp32 vector path
    const size_t need_v = 2 * norm_b + (size_t)SPLITS_V * N_ * HW_ * 8;
    if (ws_size >= need_v) {
        float* pn = (float*)d_ws;
        float* qn = pn + N_ * HW_;
        unsigned long long* partial =
            (unsigned long long*)((char*)d_ws + 2 * norm_b);
        prep_norms_kernel<<<128, 256, 0, stream>>>(s, t, pn, qn);
        dim3 grid(H_, N_, SPLITS_V);
        patchmatch_main_kernel<<<grid, 256, 0, stream>>>(s, t, pn, qn, partial);
        finalize_kernel<<<64, 256, 0, stream>>>(partial, out);
        return;
    }

    dim3 grid(H_, N_);
    patchmatch_mono_kernel<<<grid, 256, 0, stream>>>(s, t, out);
}

// Round 3
// 134.726 us; speedup vs baseline: 1.2315x; 1.2315x over previous
//
#include <hip/hip_runtime.h>

// PatchMatch brute-force NN on MI355X.
// s,t (4,16,64,64) fp32; descriptor = 3x3 replicate-padded patch, K=144.
// d2(i,j) = qn_i - 2*cross(i,j) + pn_j; argmin_j (ties -> smallest j).
// Outputs (flat, ALL FLOAT32): nnf (4,2,64,64) then nnd (4,1,64,64).
//
// R15 vs R14 (R14: 105us mfma, WRITE_SIZE 37.9MB = scratch spill):
// R14's __launch_bounds__(256,3) clamped VGPR to 84 < ~140 live state ->
// A-fragments spilled to scratch, re-read every phase through HBM.
// R15 = R14 with the clamp removed: __launch_bounds__(256,2) (R13's
// setting, compiled to 100 VGPR / 0 spill). LDS stays 51.2KB and grid
// stays 1024, so 3 blocks/CU residency is reachable via LDS+VGPR fit
// instead of being forced by the register allocator:
//  - LDS 51.2KB/block: KKSTRIDE 512, K-chunk 8 (kk16,17) loaded per-phase
//    from L2 into registers instead of DMA-staged.
//  - grid 1024 (SPLITS_M 8, 16 phases/block, j-split 512); split=bid&7
//    pins each split's B panel to one XCD's L2.
//  - uniform staging {4,4,4,4} kk-rows/wave, uniform s_waitcnt vmcnt(4).
//  - descriptor stride 18 kk rows (ws ~20MB).

#define N_  4
#define C_  16
#define H_  64
#define W_  64
#define HW_ 4096
#define KK_ 18               // kk blocks of 8 (K=144)
#define SPLITS_M 8           // j-splits; 512 j per split, 16 tiles of 32
#define KKSTRIDE 512         // f16 per kk block in LDS: 32 hi + 32 lo cols x8

#define SPLITS_V 4           // fallback j-splits
#define TILES_PER_SPLIT_V 4

typedef _Float16 f16;
typedef _Float16 f16x8 __attribute__((ext_vector_type(8)));
typedef float    f32x4 __attribute__((ext_vector_type(4)));
typedef float    f32x16 __attribute__((ext_vector_type(16)));

__device__ __forceinline__ int iclamp(int v, int lo, int hi) {
    return v < lo ? lo : (v > hi ? hi : v);
}

__device__ __forceinline__ void async_ld16(const void* g, void* l) {
    __builtin_amdgcn_global_load_lds(
        (const __attribute__((address_space(1))) unsigned int*)g,
        (__attribute__((address_space(3))) unsigned int*)l, 16, 0, 0);
}

// ---------------------------------------------------------------------------
// Kernel 1: K-major fp16 hi/lo descriptors + squared norms.
// D[(n*18 + kk)*4096 + pix][8], kk = k/8, k = d*16 + c (d = dy*3+dx).
// One block per image row; wave q handles kk = q*5..q*5+4 for all 64 px ->
// every store is a 1KB coalesced wavefront store. grid (64, N_, 2).
// ---------------------------------------------------------------------------
__global__ __launch_bounds__(256)
void build_desc_norms_kernel(const float* __restrict__ s,
                             const float* __restrict__ t,
                             f16* __restrict__ Qh, f16* __restrict__ Ql,
                             f16* __restrict__ Ph, f16* __restrict__ Pl,
                             float* __restrict__ pn,
                             float* __restrict__ qn) {
    const int y0  = blockIdx.x;                 // image row
    const int n   = blockIdx.y;
    const int src = blockIdx.z;                 // 0: t, 1: s
    const float* img = (src ? s : t) + n * (C_ * HW_);
    f16* Dh = src ? Qh : Ph;
    f16* Dl = src ? Ql : Pl;
    float* nrm = src ? qn : pn;

    __shared__ float imgS[3][C_][W_];           // 12 KB: rows y0-1..y0+1
    __shared__ float nS[4][W_];
    const int tid = threadIdx.x;
    #pragma unroll
    for (int k = 0; k < 12; ++k) {
        const int idx = tid + k * 256;          // 0..3071
        const int x = idx & 63, c = (idx >> 6) & 15, r = idx >> 10;  // r 0..2
        const int gy = iclamp(y0 + r - 1, 0, H_ - 1);
        imgS[r][c][x] = img[c * HW_ + gy * W_ + x];
    }
    __syncthreads();

    const int q = tid >> 6, x = tid & 63;       // wave, lane(=pixel x)
    const int pix = y0 * W_ + x;
    float nacc = 0.f;
    #pragma unroll
    for (int u = 0; u < 5; ++u) {
        const int kk = q * 5 + u;               // 0..19
        if (kk < KK_) {
            f16x8 hv, lv;
            const int d  = kk >> 1;             // 0..8
            const int c0 = (kk & 1) * 8;
            const int dy = (d * 11) >> 5;       // d/3 for d in [0,8]
            const int dx = d - dy * 3;
            const int xs = iclamp(x + dx - 1, 0, W_ - 1);
            #pragma unroll
            for (int cc = 0; cc < 8; ++cc) {
                const float v = imgS[dy][c0 + cc][xs];
                const f16 h = (f16)v;
                hv[cc] = h;
                lv[cc] = (f16)(v - (float)h);
                nacc += v * v;
            }
            const size_t off = ((size_t)(n * KK_ + kk) * HW_ + pix) * 8;
            *(f16x8*)&Dh[off] = hv;             // 64 lanes x 16B contiguous
            *(f16x8*)&Dl[off] = lv;
        }
    }
    nS[q][x] = nacc;
    __syncthreads();
    if (tid < W_)
        nrm[n * HW_ + pix] = nS[0][tid] + nS[1][tid] + nS[2][tid] + nS[3][tid];
}

// ---------------------------------------------------------------------------
// Kernel 2: MFMA GEMM + fused argmax. 1D grid 1024 blocks (split=bid&7 ->
// one split per XCD); block = 4 waves, wave = one 32-row output stripe.
// j: 32-wide tiles x16/split, TRIPLE-buffered async DMA staging of K-chunks
// 0..7 (kk 0..15); K-chunk 8 (kk 16,17) loaded per-phase from L2 into regs.
// Raw s_waitcnt vmcnt(4)+s_barrier per tile (prefetch in flight across it).
// LDS per buffer: [kk 0..15][h(32 cols)|l(32 cols)][8 f16], KKSTRIDE=512.
// mfma_f32_32x32x16_f16: A/B [idx=lane&31][k=(lane>>5)*8+e];
// C col=lane&31, row=(reg&3)+8*(reg>>2)+4*(lane>>5).
// Cf initialized to -pn_j/2: argmin d2 == argmax Cf; partial stores -2*Cf.
// ---------------------------------------------------------------------------
__global__ __launch_bounds__(256, 2)
void mfma_nn_kernel(const f16* __restrict__ Qh, const f16* __restrict__ Ql,
                    const f16* __restrict__ Ph, const f16* __restrict__ Pl,
                    const float* __restrict__ pn_g,
                    unsigned long long* __restrict__ partial) {
    const int bid   = blockIdx.x;
    const int split = bid & 7;          // fixed XCD under round-robin
    const int n     = (bid >> 3) & 3;
    const int iblk  = bid >> 5;         // 0..31
    const int tid  = threadIdx.x;
    const int wave = tid >> 6, lane = tid & 63;
    const int col  = lane & 31;         // A row / B col / C col
    const int half = lane >> 5;         // k-half within a 16-chunk
    const int irow0 = iblk * 128 + wave * 32;

    __shared__ f16 B0[16 * KKSTRIDE];   // 16384 B each
    __shared__ f16 B1[16 * KKSTRIDE];
    __shared__ f16 B2[16 * KKSTRIDE];
    __shared__ float pnS[512];          // this split's pn

    // ---- A fragments, resident (72 VGPR): 9 chunks of K=16 ----
    f16x8 Ah[9], Al[9];
    #pragma unroll
    for (int c = 0; c < 9; ++c) {
        const size_t off = ((size_t)(n * KK_ + 2 * c + half) * HW_ +
                            irow0 + col) * 8;
        Ah[c] = *(const f16x8*)(Qh + off);
        Al[c] = *(const f16x8*)(Ql + off);
    }

    const int jsplit0 = split * 512;
    pnS[tid]       = pn_g[n * HW_ + jsplit0 + tid];
    pnS[tid + 256] = pn_g[n * HW_ + jsplit0 + tid + 256];

    // per-lane base for the register-loaded K-chunk 8 (kk 16+half)
    const f16* p8h = Ph + ((size_t)(n * KK_ + 16 + half) * HW_ + jsplit0) * 8;
    const f16* p8l = Pl + ((size_t)(n * KK_ + 16 + half) * HW_ + jsplit0) * 8;

    float    bd[16];
    unsigned bj[16];
    #pragma unroll
    for (int r = 0; r < 16; ++r) { bd[r] = -3.0e38f; bj[r] = 0u; }

    // staging: 16 kk rows, 4 per wave (uniform)
    const int kk0 = wave * 4;
    const f16* sbase = half ? Pl : Ph;  // lanes 0-31: hi rows, 32-63: lo rows

    #define STAGE(BUF, T)                                                     \
        {   _Pragma("unroll")                                                 \
            for (int u = 0; u < 4; ++u) {                                     \
                const int kk = kk0 + u;                                       \
                const f16* g = sbase + ((size_t)(n * KK_ + kk) * HW_ +        \
                                        jsplit0 + (T) * 32 + col) * 8;        \
                async_ld16(g, (void*)&BUF[kk * KKSTRIDE + lane * 8]);         \
            }                                                                 \
        }

    // One pipeline phase: wait(WN)+barrier, issue chunk-8 reg loads (before
    // the DMA so the compiler's wait for them leaves the new stage in
    // flight), stage tile ST into SBUF, compute tile CT from CBUF.
    #define PHASE(WN, SBUF, ST, DOST, CBUF, CT)                               \
        {   asm volatile("s_waitcnt vmcnt(" #WN ")" ::: "memory");            \
            asm volatile("s_barrier" ::: "memory");                           \
            const int j8 = (CT) * 32 + col;                                   \
            const f16x8 b8h = *(const f16x8*)(p8h + (size_t)j8 * 8);          \
            const f16x8 b8l = *(const f16x8*)(p8l + (size_t)j8 * 8);          \
            if (DOST) STAGE(SBUF, ST);                                        \
            const float pnv = -0.5f * pnS[j8];                                \
            f32x16 Cf;                                                        \
            _Pragma("unroll")                                                 \
            for (int r = 0; r < 16; ++r) Cf[r] = pnv;                         \
            __builtin_amdgcn_s_setprio(1);                                    \
            _Pragma("unroll")                                                 \
            for (int c = 0; c < 8; ++c) {                                     \
                const int kb = (2 * c + half) * KKSTRIDE + col * 8;           \
                const f16x8 bh = *(const f16x8*)&CBUF[kb];                    \
                const f16x8 bl = *(const f16x8*)&CBUF[kb + 256];              \
                Cf = __builtin_amdgcn_mfma_f32_32x32x16_f16(                  \
                    Ah[c], bh, Cf, 0, 0, 0);                                  \
                Cf = __builtin_amdgcn_mfma_f32_32x32x16_f16(                  \
                    Al[c], bh, Cf, 0, 0, 0);                                  \
                Cf = __builtin_amdgcn_mfma_f32_32x32x16_f16(                  \
                    Ah[c], bl, Cf, 0, 0, 0);                                  \
            }                                                                 \
            Cf = __builtin_amdgcn_mfma_f32_32x32x16_f16(                      \
                Ah[8], b8h, Cf, 0, 0, 0);                                     \
            Cf = __builtin_amdgcn_mfma_f32_32x32x16_f16(                      \
                Al[8], b8h, Cf, 0, 0, 0);                                     \
            Cf = __builtin_amdgcn_mfma_f32_32x32x16_f16(                      \
                Ah[8], b8l, Cf, 0, 0, 0);                                     \
            __builtin_amdgcn_s_setprio(0);                                    \
            _Pragma("unroll")                                                 \
            for (int r = 0; r < 16; ++r)                                      \
                if (Cf[r] > bd[r]) { bd[r] = Cf[r]; bj[r] = (unsigned)j8; }   \
        }

    STAGE(B0, 0)
    STAGE(B1, 1)
    __syncthreads();    // pnS + first two stages visible (one-time drain)

    for (int g = 0; g < 4; ++g) {       // tiles 0..11, stages 2..13
        const int t = g * 3;
        PHASE(4, B2, t + 2, true,  B0, t)
        PHASE(4, B0, t + 3, true,  B1, t + 1)
        PHASE(4, B1, t + 4, true,  B2, t + 2)
    }
    PHASE(4, B2, 14, true,  B0, 12)
    PHASE(4, B0, 15, true,  B1, 13)
    PHASE(4, B1, 0,  false, B2, 14)
    PHASE(0, B0, 0,  false, B0, 15)
    #undef STAGE
    #undef PHASE

    // ---- argmax reduce across the 32 cols (lanes col=0..31 per half) ----
    #pragma unroll
    for (int r = 0; r < 16; ++r) {
        float    d = bd[r];
        unsigned j = (unsigned)jsplit0 + bj[r];
        #pragma unroll
        for (int off = 1; off < 32; off <<= 1) {
            const float    od = __shfl_xor(d, off, 64);
            const unsigned oj = __shfl_xor(j, off, 64);
            const bool take = (od > d) || (od == d && oj < j);
            d = take ? od : d;
            j = take ? oj : j;
        }
        if (col == 0) {
            const int i = irow0 + (r & 3) + 8 * (r >> 2) + 4 * half;
            partial[(size_t)(split * N_ + n) * HW_ + i] =
                ((unsigned long long)j << 32) |
                (unsigned long long)__float_as_uint(-2.f * d);
        }
    }
}

// ---------------------------------------------------------------------------
// Kernel 3: reduce splits, add qn, decode, write outputs (float32)
// ---------------------------------------------------------------------------
__global__ __launch_bounds__(256)
void finalize_mfma_kernel(const unsigned long long* __restrict__ partial,
                          const float* __restrict__ qn_g,
                          float* __restrict__ out) {
    const int id  = blockIdx.x * 256 + threadIdx.x;   // 0..16383
    const int n   = id >> 12;
    const int pix = id & 4095;
    float    bd = 3.0e38f;
    unsigned bj = 0u;
    #pragma unroll
    for (int sp = 0; sp < SPLITS_M; ++sp) {
        const unsigned long long v = partial[(size_t)(sp * N_ + n) * HW_ + pix];
        const float    d = __uint_as_float((unsigned)(v & 0xffffffffull));
        const unsigned j = (unsigned)(v >> 32);
        const bool take = (d < bd) || (d == bd && j < bj);
        bd = take ? d : bd;
        bj = take ? j : bj;
    }
    out[n * 2 * HW_ + pix]            = (float)(bj >> 6);          // idy
    out[n * 2 * HW_ + HW_ + pix]      = (float)(bj & 63);          // idx_x
    out[N_ * 2 * HW_ + n * HW_ + pix] = bd + qn_g[n * HW_ + pix];  // nnd
}

// ===========================================================================
// Fallback path (fp32 vector) + helpers — unchanged
// ===========================================================================
__global__ __launch_bounds__(256)
void prep_norms_kernel(const float* __restrict__ s,
                       const float* __restrict__ t,
                       float* __restrict__ pn,
                       float* __restrict__ qn) {
    const int gid   = blockIdx.x * 256 + threadIdx.x;
    const int which = gid >> 14;
    const int id    = gid & 16383;
    const int n     = id >> 12;
    const int pix   = id & 4095;
    const int y = pix >> 6, x = pix & 63;
    const float* base = (which ? s : t) + n * (C_ * HW_);
    float acc = 0.f;
    for (int c = 0; c < C_; ++c) {
        const float* bc = base + c * HW_;
        #pragma unroll
        for (int dy = 0; dy < 3; ++dy) {
            const float* br = bc + iclamp(y + dy - 1, 0, H_ - 1) * W_;
            #pragma unroll
            for (int dx = 0; dx < 3; ++dx) {
                float v = br[iclamp(x + dx - 1, 0, W_ - 1)];
                acc += v * v;
            }
        }
    }
    (which ? qn : pn)[id] = acc;
}

__global__ __launch_bounds__(256)
void patchmatch_main_kernel(const float* __restrict__ s,
                            const float* __restrict__ t,
                            const float* __restrict__ pn_g,
                            const float* __restrict__ qn_g,
                            unsigned long long* __restrict__ partial) {
    const int yq    = blockIdx.x;
    const int n     = blockIdx.y;
    const int split = blockIdx.z;
    const int tid  = threadIdx.x;
    const int tx   = tid & 15;
    const int ty   = tid >> 4;
    const int i0   = ty * 4;
    const int jrow = tx >> 2;
    const int jx0  = (tx & 3) * 16;

    __shared__ float qS[C_][3][68];
    __shared__ float tS[C_][6][68];
    __shared__ float qnS[W_];

    const float* sb = s + n * (C_ * HW_);
    const float* tb = t + n * (C_ * HW_);

    #pragma unroll
    for (int k = 0; k < 3; ++k) {
        const int id = tid + k * 256;
        const int sg = id & 15;
        const int c  = (id >> 4) & 15;
        const int r  = id >> 8;
        const int gr = iclamp(yq + r - 1, 0, H_ - 1);
        const float4 v = *(const float4*)&sb[c * HW_ + gr * W_ + sg * 4];
        float* dst = &qS[c][r][1 + sg * 4];
        dst[0] = v.x; dst[1] = v.y; dst[2] = v.z; dst[3] = v.w;
    }
    if (tid < 48) {
        const int c  = tid & 15;
        const int r  = tid >> 4;
        const int gr = iclamp(yq + r - 1, 0, H_ - 1);
        qS[c][r][0]  = sb[c * HW_ + gr * W_];
        qS[c][r][65] = sb[c * HW_ + gr * W_ + 63];
    }
    if (tid < W_) qnS[tid] = qn_g[n * HW_ + yq * W_ + tid];

    unsigned long long best[4] = {~0ull, ~0ull, ~0ull, ~0ull};

    for (int ytl = 0; ytl < TILES_PER_SPLIT_V; ++ytl) {
        const int yt = split * TILES_PER_SPLIT_V + ytl;
        __syncthreads();
        #pragma unroll
        for (int k = 0; k < 6; ++k) {
            const int id = tid + k * 256;
            const int sg = id & 15;
            const int c  = (id >> 4) & 15;
            const int r  = id >> 8;
            const int gr = iclamp(4 * yt + r - 1, 0, H_ - 1);
            const float4 v = *(const float4*)&tb[c * HW_ + gr * W_ + sg * 4];
            float* dst = &tS[c][r][1 + sg * 4];
            dst[0] = v.x; dst[1] = v.y; dst[2] = v.z; dst[3] = v.w;
        }
        if (tid < 96) {
            const int c  = tid & 15;
            const int r  = tid >> 4;
            const int gr = iclamp(4 * yt + r - 1, 0, H_ - 1);
            tS[c][r][0]  = tb[c * HW_ + gr * W_];
            tS[c][r][65] = tb[c * HW_ + gr * W_ + 63];
        }
        __syncthreads();

        float acc[4][16];
        #pragma unroll
        for (int a = 0; a < 4; ++a)
            #pragma unroll
            for (int b = 0; b < 16; ++b) acc[a][b] = 0.f;

        for (int c = 0; c < C_; ++c) {
            #pragma unroll
            for (int dy = 0; dy < 3; ++dy) {
                float qv[6], tv[18];
                *(float4*)&qv[0] = *(const float4*)&qS[c][dy][i0];
                *(float2*)&qv[4] = *(const float2*)&qS[c][dy][i0 + 4];
                const float* trow = &tS[c][jrow + dy][jx0];
                *(float4*)&tv[0]  = *(const float4*)&trow[0];
                *(float4*)&tv[4]  = *(const float4*)&trow[4];
                *(float4*)&tv[8]  = *(const float4*)&trow[8];
                *(float4*)&tv[12] = *(const float4*)&trow[12];
                *(float2*)&tv[16] = *(const float2*)&trow[16];
                #pragma unroll
                for (int dx = 0; dx < 3; ++dx)
                    #pragma unroll
                    for (int a = 0; a < 4; ++a)
                        #pragma unroll
                        for (int b = 0; b < 16; ++b)
                            acc[a][b] += qv[a + dx] * tv[b + dx];
            }
        }

        const int jbase = yt * 256 + jrow * W_ + jx0;
        float pnv[16];
        const float* png = &pn_g[n * HW_ + jbase];
        *(float4*)&pnv[0]  = *(const float4*)&png[0];
        *(float4*)&pnv[4]  = *(const float4*)&png[4];
        *(float4*)&pnv[8]  = *(const float4*)&png[8];
        *(float4*)&pnv[12] = *(const float4*)&png[12];
        #pragma unroll
        for (int a = 0; a < 4; ++a) {
            const float qn = qnS[i0 + a];
            #pragma unroll
            for (int b = 0; b < 16; ++b) {
                const float d2 = qn + pnv[b] - 2.f * acc[a][b];
                unsigned long long cand =
                    ((unsigned long long)__float_as_uint(d2) << 32) |
                    (unsigned)(jbase + b);
                best[a] = cand < best[a] ? cand : best[a];
            }
        }
    }

    #pragma unroll
    for (int a = 0; a < 4; ++a) {
        unsigned long long v = best[a];
        #pragma unroll
        for (int mm = 8; mm >= 1; mm >>= 1) {
            unsigned long long o = __shfl_xor(v, mm, 64);
            v = o < v ? o : v;
        }
        best[a] = v;
    }
    if (tx == 0) {
        #pragma unroll
        for (int a = 0; a < 4; ++a)
            partial[((split * N_ + n) * HW_) + yq * W_ + i0 + a] = best[a];
    }
}

__global__ __launch_bounds__(256)
void finalize_kernel(const unsigned long long* __restrict__ partial,
                     float* __restrict__ out) {
    const int id  = blockIdx.x * 256 + threadIdx.x;
    const int n   = id >> 12;
    const int pix = id & 4095;
    unsigned long long best = ~0ull;
    #pragma unroll
    for (int sp = 0; sp < SPLITS_V; ++sp) {
        unsigned long long v = partial[(sp * N_ + n) * HW_ + pix];
        best = v < best ? v : best;
    }
    const unsigned j = (unsigned)(best & 0xffffffffu);
    const float d2 = __uint_as_float((unsigned)(best >> 32));
    out[n * 2 * HW_ + pix]            = (float)(j >> 6);
    out[n * 2 * HW_ + HW_ + pix]      = (float)(j & 63);
    out[N_ * 2 * HW_ + n * HW_ + pix] = d2;
}

__global__ __launch_bounds__(256)
void patchmatch_mono_kernel(const float* __restrict__ s,
                            const float* __restrict__ t,
                            float* __restrict__ out) {
    const int yq  = blockIdx.x;
    const int n   = blockIdx.y;
    const int tid = threadIdx.x;
    const int tx  = tid & 15;
    const int ty  = tid >> 4;
    const int i0  = ty * 4;
    const int jrow = tx >> 3;
    const int jx0  = (tx & 7) * 8;

    __shared__ float qS[C_][3][68];
    __shared__ float tS[C_][4][68];
    __shared__ float pnS[HW_];
    __shared__ float qnS[W_];

    const float* sb = s + n * (C_ * HW_);
    const float* tb = t + n * (C_ * HW_);

    for (int jj = tid; jj < HW_; jj += 256) {
        const int y = jj >> 6, x = jj & 63;
        float acc = 0.f;
        for (int c = 0; c < C_; ++c) {
            const float* tc = tb + c * HW_;
            #pragma unroll
            for (int dy = 0; dy < 3; ++dy) {
                const float* tr = tc + iclamp(y + dy - 1, 0, H_ - 1) * W_;
                #pragma unroll
                for (int dx = 0; dx < 3; ++dx) {
                    float v = tr[iclamp(x + dx - 1, 0, W_ - 1)];
                    acc += v * v;
                }
            }
        }
        pnS[jj] = acc;
    }
    for (int idx = tid; idx < C_ * 3 * 66; idx += 256) {
        const int c   = idx / (3 * 66);
        const int rem = idx - c * (3 * 66);
        const int rr  = rem / 66;
        const int xi  = rem - rr * 66;
        qS[c][rr][xi] = sb[c * HW_ + iclamp(yq + rr - 1, 0, H_ - 1) * W_ +
                           iclamp(xi - 1, 0, W_ - 1)];
    }
    __syncthreads();
    if (tid < W_) {
        float acc = 0.f;
        for (int c = 0; c < C_; ++c)
            #pragma unroll
            for (int dy = 0; dy < 3; ++dy)
                #pragma unroll
                for (int dx = 0; dx < 3; ++dx) {
                    float v = qS[c][dy][tid + dx];
                    acc += v * v;
                }
        qnS[tid] = acc;
    }

    unsigned long long best[4] = {~0ull, ~0ull, ~0ull, ~0ull};
    for (int yt = 0; yt < 32; ++yt) {
        __syncthreads();
        for (int idx = tid; idx < C_ * 4 * 66; idx += 256) {
            const int c   = idx / (4 * 66);
            const int rem = idx - c * (4 * 66);
            const int rr  = rem / 66;
            const int xi  = rem - rr * 66;
            tS[c][rr][xi] = tb[c * HW_ + iclamp(2 * yt + rr - 1, 0, H_ - 1) * W_ +
                               iclamp(xi - 1, 0, W_ - 1)];
        }
        __syncthreads();

        float acc[4][8];
        #pragma unroll
        for (int a = 0; a < 4; ++a)
            #pragma unroll
            for (int b = 0; b < 8; ++b) acc[a][b] = 0.f;

        for (int c = 0; c < C_; ++c) {
            #pragma unroll
            for (int dy = 0; dy < 3; ++dy) {
                float qv[8], tv[12];
                *(float4*)&qv[0] = *(const float4*)&qS[c][dy][i0];
                *(float4*)&qv[4] = *(const float4*)&qS[c][dy][i0 + 4];
                const float* trow = &tS[c][jrow + dy][jx0];
                *(float4*)&tv[0] = *(const float4*)&trow[0];
                *(float4*)&tv[4] = *(const float4*)&trow[4];
                *(float4*)&tv[8] = *(const float4*)&trow[8];
                #pragma unroll
                for (int dx = 0; dx < 3; ++dx)
                    #pragma unroll
                    for (int a = 0; a < 4; ++a)
                        #pragma unroll
                        for (int b = 0; b < 8; ++b)
                            acc[a][b] += qv[a + dx] * tv[b + dx];
            }
        }
        const int rbase = (2 * yt + jrow) * W_ + jx0;
        #pragma unroll
        for (int a = 0; a < 4; ++a) {
            const float qn = qnS[i0 + a];
            #pragma unroll
            for (int b = 0; b < 8; ++b) {
                const int j = rbase + b;
                const float d2 = qn + pnS[j] - 2.f * acc[a][b];
                unsigned long long cand =
                    ((unsigned long long)__float_as_uint(d2) << 32) | (unsigned)j;
                best[a] = cand < best[a] ? cand : best[a];
            }
        }
    }
    #pragma unroll
    for (int a = 0; a < 4; ++a) {
        unsigned long long v = best[a];
        #pragma unroll
        for (int mm = 8; mm >= 1; mm >>= 1) {
            unsigned long long o = __shfl_xor(v, mm, 64);
            v = o < v ? o : v;
        }
        best[a] = v;
    }
    if (tx == 0) {
        #pragma unroll
        for (int a = 0; a < 4; ++a) {
            const int x = i0 + a;
            const unsigned j = (unsigned)(best[a] & 0xffffffffu);
            const float d2 = __uint_as_float((unsigned)(best[a] >> 32));
            const int pix = yq * W_ + x;
            out[n * 2 * HW_ + pix]            = (float)(j >> 6);
            out[n * 2 * HW_ + HW_ + pix]      = (float)(j & 63);
            out[N_ * 2 * HW_ + n * HW_ + pix] = d2;
        }
    }
}

// ===========================================================================
extern "C" void kernel_launch(void* const* d_in, const int* in_sizes, int n_in,
                              void* d_out, int out_size, void* d_ws, size_t ws_size,
                              hipStream_t stream) {
    const float* s = (const float*)d_in[0];
    const float* t = (const float*)d_in[1];
    float* out = (float*)d_out;

    // MFMA ws layout:
    //   pn [4][4096] f32 | qn [4][4096] f32 | partial [8][4][4096] u64 |
    //   Qh | Ql | Ph | Pl   each K-major [4][18][4096][8] f16 (4.72 MB)
    const size_t norm_b  = (size_t)N_ * HW_ * 4;
    const size_t part_b  = (size_t)SPLITS_M * N_ * HW_ * 8;
    const size_t desc_b  = (size_t)N_ * HW_ * KK_ * 8 * 2;
    const size_t need_m  = 2 * norm_b + part_b + 4 * desc_b;     // ~20.1 MB

    if (ws_size >= need_m) {
        char* w = (char*)d_ws;
        float* pn = (float*)w;                       w += norm_b;
        float* qn = (float*)w;                       w += norm_b;
        unsigned long long* partial = (unsigned long long*)w; w += part_b;
        f16* Qh = (f16*)w;  w += desc_b;
        f16* Ql = (f16*)w;  w += desc_b;
        f16* Ph = (f16*)w;  w += desc_b;
        f16* Pl = (f16*)w;

        build_desc_norms_kernel<<<dim3(64, N_, 2), 256, 0, stream>>>(
            s, t, Qh, Ql, Ph, Pl, pn, qn);
        mfma_nn_kernel<<<1024, 256, 0, stream>>>(Qh, Ql, Ph, Pl, pn, partial);
        finalize_mfma_kernel<<<64, 256, 0, stream>>>(partial, qn, out);
        return;
    }

    // Fallback: fp32 vector path
    const size_t need_v = 2 * norm_b + (size_t)SPLITS_V * N_ * HW_ * 8;
    if (ws_size >= need_v) {
        float* pn = (float*)d_ws;
        float* qn = pn + N_ * HW_;
        unsigned long long* partial =
            (unsigned long long*)((char*)d_ws + 2 * norm_b);
        prep_norms_kernel<<<128, 256, 0, stream>>>(s, t, pn, qn);
        dim3 grid(H_, N_, SPLITS_V);
        patchmatch_main_kernel<<<grid, 256, 0, stream>>>(s, t, pn, qn, partial);
        finalize_kernel<<<64, 256, 0, stream>>>(partial, out);
        return;
    }

    dim3 grid(H_, N_);
    patchmatch_mono_kernel<<<grid, 256, 0, stream>>>(s, t, out);
}

// Round 4
// 124.370 us; speedup vs baseline: 1.3340x; 1.0833x over previous
//
#include <hip/hip_runtime.h>

// PatchMatch brute-force NN on MI355X.
// s,t (4,16,64,64) fp32; descriptor = 3x3 replicate-padded patch, K=144.
// d2(i,j) = qn_i - 2*cross(i,j) + pn_j; argmin_j (ties -> smallest j).
// Outputs (flat, ALL FLOAT32): nnf (4,2,64,64) then nnd (4,1,64,64).
//
// R16 vs R15/R13: phase time measured invariant to compute content
// (R12 60-MFMA phases == R13 27-MFMA phases == ~4800 cyc) -> each phase is
// overhead-bound (barrier+vmcnt+LDS latency+dependent chain), every pipe
// <40% busy. R15 (split 8) also showed split-4/grid-512 is the better frame
// (half the A re-fetch, no 2nd dispatch round). So R16:
//  - grid 512 (SPLITS_M 4), 2 blocks/CU, single round (R13 frame).
//  - 16 phases x TWO 32-wide j-tiles per phase: two independent 27-MFMA
//    chains (ILP 2), ONE vmcnt+barrier per phase (half of R13).
//  - all 18 kk rows staged; 4 LDS buffers (2 pairs) x 18KB + pn 4KB =
//    77.8KB -> 2 blocks/CU. 9 DMAs/wave/phase, uniform.
//  - vmcnt(0) at phase start: drains loads issued a full phase earlier
//    (~free); this phase's 9 DMAs stay in flight across the compute.
//  - Cf init -pn_j/2 (argmin == argmax), partial stores -2*Cf.

#define N_  4
#define C_  16
#define H_  64
#define W_  64
#define HW_ 4096
#define KK_ 18               // kk blocks of 8 (K=144)
#define SPLITS_M 4           // j-splits; 1024 j per split, 32 tiles of 32
#define KKSTRIDE 512         // f16 per kk block in LDS: 32 hi + 32 lo cols x8

#define SPLITS_V 4           // fallback j-splits
#define TILES_PER_SPLIT_V 4

typedef _Float16 f16;
typedef _Float16 f16x8 __attribute__((ext_vector_type(8)));
typedef float    f32x4 __attribute__((ext_vector_type(4)));
typedef float    f32x16 __attribute__((ext_vector_type(16)));

__device__ __forceinline__ int iclamp(int v, int lo, int hi) {
    return v < lo ? lo : (v > hi ? hi : v);
}

__device__ __forceinline__ void async_ld16(const void* g, void* l) {
    __builtin_amdgcn_global_load_lds(
        (const __attribute__((address_space(1))) unsigned int*)g,
        (__attribute__((address_space(3))) unsigned int*)l, 16, 0, 0);
}

// ---------------------------------------------------------------------------
// Kernel 1: K-major fp16 hi/lo descriptors + squared norms.
// D[(n*18 + kk)*4096 + pix][8], kk = k/8, k = d*16 + c (d = dy*3+dx).
// One block per image row; wave q handles kk = q*5..q*5+4 for all 64 px ->
// every store is a 1KB coalesced wavefront store. grid (64, N_, 2).
// ---------------------------------------------------------------------------
__global__ __launch_bounds__(256)
void build_desc_norms_kernel(const float* __restrict__ s,
                             const float* __restrict__ t,
                             f16* __restrict__ Qh, f16* __restrict__ Ql,
                             f16* __restrict__ Ph, f16* __restrict__ Pl,
                             float* __restrict__ pn,
                             float* __restrict__ qn) {
    const int y0  = blockIdx.x;                 // image row
    const int n   = blockIdx.y;
    const int src = blockIdx.z;                 // 0: t, 1: s
    const float* img = (src ? s : t) + n * (C_ * HW_);
    f16* Dh = src ? Qh : Ph;
    f16* Dl = src ? Ql : Pl;
    float* nrm = src ? qn : pn;

    __shared__ float imgS[3][C_][W_];           // 12 KB: rows y0-1..y0+1
    __shared__ float nS[4][W_];
    const int tid = threadIdx.x;
    #pragma unroll
    for (int k = 0; k < 12; ++k) {
        const int idx = tid + k * 256;          // 0..3071
        const int x = idx & 63, c = (idx >> 6) & 15, r = idx >> 10;  // r 0..2
        const int gy = iclamp(y0 + r - 1, 0, H_ - 1);
        imgS[r][c][x] = img[c * HW_ + gy * W_ + x];
    }
    __syncthreads();

    const int q = tid >> 6, x = tid & 63;       // wave, lane(=pixel x)
    const int pix = y0 * W_ + x;
    float nacc = 0.f;
    #pragma unroll
    for (int u = 0; u < 5; ++u) {
        const int kk = q * 5 + u;               // 0..19
        if (kk < KK_) {
            f16x8 hv, lv;
            const int d  = kk >> 1;             // 0..8
            const int c0 = (kk & 1) * 8;
            const int dy = (d * 11) >> 5;       // d/3 for d in [0,8]
            const int dx = d - dy * 3;
            const int xs = iclamp(x + dx - 1, 0, W_ - 1);
            #pragma unroll
            for (int cc = 0; cc < 8; ++cc) {
                const float v = imgS[dy][c0 + cc][xs];
                const f16 h = (f16)v;
                hv[cc] = h;
                lv[cc] = (f16)(v - (float)h);
                nacc += v * v;
            }
            const size_t off = ((size_t)(n * KK_ + kk) * HW_ + pix) * 8;
            *(f16x8*)&Dh[off] = hv;             // 64 lanes x 16B contiguous
            *(f16x8*)&Dl[off] = lv;
        }
    }
    nS[q][x] = nacc;
    __syncthreads();
    if (tid < W_)
        nrm[n * HW_ + pix] = nS[0][tid] + nS[1][tid] + nS[2][tid] + nS[3][tid];
}

// ---------------------------------------------------------------------------
// Kernel 2: MFMA GEMM + fused argmax. 1D grid 512 (split=bid&3, XCD-pinned
// under round-robin); block = 4 waves, wave = one 32-row output stripe.
// j: 1024 per split = 16 phases x two 32-wide tiles. Double-buffered pairs
// (4 LDS buffers); one vmcnt(0)+s_barrier per phase; 9 DMAs/wave/phase
// issued right after the barrier stay in flight across the compute.
// LDS buffer: [kk 0..17][h(32 cols)|l(32 cols)][8 f16], KKSTRIDE=512.
// mfma_f32_32x32x16_f16: A/B [idx=lane&31][k=(lane>>5)*8+e];
// C col=lane&31, row=(reg&3)+8*(reg>>2)+4*(lane>>5).
// Cf initialized to -pn_j/2: argmin d2 == argmax Cf; partial stores -2*Cf.
// ---------------------------------------------------------------------------
__global__ __launch_bounds__(256, 2)
void mfma_nn_kernel(const f16* __restrict__ Qh, const f16* __restrict__ Ql,
                    const f16* __restrict__ Ph, const f16* __restrict__ Pl,
                    const float* __restrict__ pn_g,
                    unsigned long long* __restrict__ partial) {
    const int bid   = blockIdx.x;
    const int split = bid & 3;          // XCD affinity under round-robin
    const int n     = (bid >> 2) & 3;
    const int iblk  = bid >> 4;         // 0..31
    const int tid  = threadIdx.x;
    const int wave = tid >> 6, lane = tid & 63;
    const int col  = lane & 31;         // A row / B col / C col
    const int half = lane >> 5;         // k-half within a 16-chunk
    const int irow0 = iblk * 128 + wave * 32;

    __shared__ f16 Bbuf[4][KK_ * KKSTRIDE];   // 4 x 18432 B; pairs {0,1},{2,3}
    __shared__ float pnS[1024];               // this split's pn

    // ---- A fragments, resident (72 VGPR): 9 chunks of K=16 ----
    f16x8 Ah[9], Al[9];
    #pragma unroll
    for (int c = 0; c < 9; ++c) {
        const size_t off = ((size_t)(n * KK_ + 2 * c + half) * HW_ +
                            irow0 + col) * 8;
        Ah[c] = *(const f16x8*)(Qh + off);
        Al[c] = *(const f16x8*)(Ql + off);
    }

    const int jsplit0 = split * 1024;
    #pragma unroll
    for (int k = 0; k < 4; ++k)
        pnS[tid + k * 256] = pn_g[n * HW_ + jsplit0 + tid + k * 256];

    float    bd[16];
    unsigned bj[16];
    #pragma unroll
    for (int r = 0; r < 16; ++r) { bd[r] = -3.0e38f; bj[r] = 0u; }

    // staging: 2 tiles x 18 kk rows = 36 DMAs, 9 per wave (uniform).
    // wave>>1 picks the tile of the pair; wave&1 picks rows 0-8 / 9-17.
    const int stile = wave >> 1;
    const int skk0  = (wave & 1) * 9;
    const f16* sbase = half ? Pl : Ph;  // lanes 0-31: hi rows, 32-63: lo rows

    #define STAGE(PAIR, T0)                                                   \
        {   _Pragma("unroll")                                                 \
            for (int u = 0; u < 9; ++u) {                                     \
                const int kk = skk0 + u;                                      \
                const f16* g = sbase + ((size_t)(n * KK_ + kk) * HW_ +        \
                                        jsplit0 + ((T0) + stile) * 32 +       \
                                        col) * 8;                             \
                async_ld16(g, (void*)&Bbuf[(PAIR) * 2 + stile]                \
                                          [kk * KKSTRIDE + lane * 8]);        \
            }                                                                 \
        }

    #define BAR()                                                             \
        {   asm volatile("s_waitcnt vmcnt(0)" ::: "memory");                  \
            asm volatile("s_barrier" ::: "memory");                           \
        }

    // Two 32-wide tiles (T0, T0+1) from buffer pair PAIR: two independent
    // 27-MFMA chains interleaved by the compiler.
    #define COMPUTE2(PAIR, T0)                                                \
        {   const int j0 = (T0) * 32 + col;                                   \
            const float pnv0 = -0.5f * pnS[j0];                               \
            const float pnv1 = -0.5f * pnS[j0 + 32];                          \
            f32x16 C0, C1;                                                    \
            _Pragma("unroll")                                                 \
            for (int r = 0; r < 16; ++r) { C0[r] = pnv0; C1[r] = pnv1; }      \
            __builtin_amdgcn_s_setprio(1);                                    \
            _Pragma("unroll")                                                 \
            for (int c = 0; c < 9; ++c) {                                     \
                const int kb = (2 * c + half) * KKSTRIDE + col * 8;           \
                const f16x8 bh0 = *(const f16x8*)&Bbuf[(PAIR) * 2][kb];       \
                const f16x8 bl0 = *(const f16x8*)&Bbuf[(PAIR) * 2][kb + 256]; \
                const f16x8 bh1 = *(const f16x8*)&Bbuf[(PAIR) * 2 + 1][kb];   \
                const f16x8 bl1 = *(const f16x8*)&Bbuf[(PAIR) * 2 + 1]        \
                                                      [kb + 256];             \
                C0 = __builtin_amdgcn_mfma_f32_32x32x16_f16(                  \
                    Ah[c], bh0, C0, 0, 0, 0);                                 \
                C1 = __builtin_amdgcn_mfma_f32_32x32x16_f16(                  \
                    Ah[c], bh1, C1, 0, 0, 0);                                 \
                C0 = __builtin_amdgcn_mfma_f32_32x32x16_f16(                  \
                    Al[c], bh0, C0, 0, 0, 0);                                 \
                C1 = __builtin_amdgcn_mfma_f32_32x32x16_f16(                  \
                    Al[c], bh1, C1, 0, 0, 0);                                 \
                C0 = __builtin_amdgcn_mfma_f32_32x32x16_f16(                  \
                    Ah[c], bl0, C0, 0, 0, 0);                                 \
                C1 = __builtin_amdgcn_mfma_f32_32x32x16_f16(                  \
                    Ah[c], bl1, C1, 0, 0, 0);                                 \
            }                                                                 \
            __builtin_amdgcn_s_setprio(0);                                    \
            _Pragma("unroll")                                                 \
            for (int r = 0; r < 16; ++r) {                                    \
                if (C0[r] > bd[r]) { bd[r] = C0[r]; bj[r] = (unsigned)j0; }   \
                if (C1[r] > bd[r]) { bd[r] = C1[r];                           \
                                     bj[r] = (unsigned)(j0 + 32); }           \
            }                                                                 \
        }

    STAGE(0, 0)                        // P0 = tiles 0,1 -> pair 0
    asm volatile("s_waitcnt vmcnt(0)" ::: "memory");
    __syncthreads();                   // pnS + P0 visible

    STAGE(1, 2)  COMPUTE2(0, 0)        // phase 0
    for (int gg = 0; gg < 6; ++gg) {   // phases 1..12
        const int t4 = gg * 4;
        BAR()  STAGE(0, t4 + 4)  COMPUTE2(1, t4 + 2)
        BAR()  STAGE(1, t4 + 6)  COMPUTE2(0, t4 + 4)
    }
    BAR()  STAGE(0, 28)  COMPUTE2(1, 26)   // phase 13
    BAR()  STAGE(1, 30)  COMPUTE2(0, 28)   // phase 14
    BAR()               COMPUTE2(1, 30)    // phase 15
    #undef STAGE
    #undef BAR
    #undef COMPUTE2

    // ---- argmax reduce across the 32 cols (lanes col=0..31 per half) ----
    #pragma unroll
    for (int r = 0; r < 16; ++r) {
        float    d = bd[r];
        unsigned j = (unsigned)jsplit0 + bj[r];
        #pragma unroll
        for (int off = 1; off < 32; off <<= 1) {
            const float    od = __shfl_xor(d, off, 64);
            const unsigned oj = __shfl_xor(j, off, 64);
            const bool take = (od > d) || (od == d && oj < j);
            d = take ? od : d;
            j = take ? oj : j;
        }
        if (col == 0) {
            const int i = irow0 + (r & 3) + 8 * (r >> 2) + 4 * half;
            partial[(size_t)(split * N_ + n) * HW_ + i] =
                ((unsigned long long)j << 32) |
                (unsigned long long)__float_as_uint(-2.f * d);
        }
    }
}

// ---------------------------------------------------------------------------
// Kernel 3: reduce splits, add qn, decode, write outputs (float32)
// ---------------------------------------------------------------------------
__global__ __launch_bounds__(256)
void finalize_mfma_kernel(const unsigned long long* __restrict__ partial,
                          const float* __restrict__ qn_g,
                          float* __restrict__ out) {
    const int id  = blockIdx.x * 256 + threadIdx.x;   // 0..16383
    const int n   = id >> 12;
    const int pix = id & 4095;
    float    bd = 3.0e38f;
    unsigned bj = 0u;
    #pragma unroll
    for (int sp = 0; sp < SPLITS_M; ++sp) {
        const unsigned long long v = partial[(size_t)(sp * N_ + n) * HW_ + pix];
        const float    d = __uint_as_float((unsigned)(v & 0xffffffffull));
        const unsigned j = (unsigned)(v >> 32);
        const bool take = (d < bd) || (d == bd && j < bj);
        bd = take ? d : bd;
        bj = take ? j : bj;
    }
    out[n * 2 * HW_ + pix]            = (float)(bj >> 6);          // idy
    out[n * 2 * HW_ + HW_ + pix]      = (float)(bj & 63);          // idx_x
    out[N_ * 2 * HW_ + n * HW_ + pix] = bd + qn_g[n * HW_ + pix];  // nnd
}

// ===========================================================================
// Fallback path (fp32 vector) + helpers — unchanged
// ===========================================================================
__global__ __launch_bounds__(256)
void prep_norms_kernel(const float* __restrict__ s,
                       const float* __restrict__ t,
                       float* __restrict__ pn,
                       float* __restrict__ qn) {
    const int gid   = blockIdx.x * 256 + threadIdx.x;
    const int which = gid >> 14;
    const int id    = gid & 16383;
    const int n     = id >> 12;
    const int pix   = id & 4095;
    const int y = pix >> 6, x = pix & 63;
    const float* base = (which ? s : t) + n * (C_ * HW_);
    float acc = 0.f;
    for (int c = 0; c < C_; ++c) {
        const float* bc = base + c * HW_;
        #pragma unroll
        for (int dy = 0; dy < 3; ++dy) {
            const float* br = bc + iclamp(y + dy - 1, 0, H_ - 1) * W_;
            #pragma unroll
            for (int dx = 0; dx < 3; ++dx) {
                float v = br[iclamp(x + dx - 1, 0, W_ - 1)];
                acc += v * v;
            }
        }
    }
    (which ? qn : pn)[id] = acc;
}

__global__ __launch_bounds__(256)
void patchmatch_main_kernel(const float* __restrict__ s,
                            const float* __restrict__ t,
                            const float* __restrict__ pn_g,
                            const float* __restrict__ qn_g,
                            unsigned long long* __restrict__ partial) {
    const int yq    = blockIdx.x;
    const int n     = blockIdx.y;
    const int split = blockIdx.z;
    const int tid  = threadIdx.x;
    const int tx   = tid & 15;
    const int ty   = tid >> 4;
    const int i0   = ty * 4;
    const int jrow = tx >> 2;
    const int jx0  = (tx & 3) * 16;

    __shared__ float qS[C_][3][68];
    __shared__ float tS[C_][6][68];
    __shared__ float qnS[W_];

    const float* sb = s + n * (C_ * HW_);
    const float* tb = t + n * (C_ * HW_);

    #pragma unroll
    for (int k = 0; k < 3; ++k) {
        const int id = tid + k * 256;
        const int sg = id & 15;
        const int c  = (id >> 4) & 15;
        const int r  = id >> 8;
        const int gr = iclamp(yq + r - 1, 0, H_ - 1);
        const float4 v = *(const float4*)&sb[c * HW_ + gr * W_ + sg * 4];
        float* dst = &qS[c][r][1 + sg * 4];
        dst[0] = v.x; dst[1] = v.y; dst[2] = v.z; dst[3] = v.w;
    }
    if (tid < 48) {
        const int c  = tid & 15;
        const int r  = tid >> 4;
        const int gr = iclamp(yq + r - 1, 0, H_ - 1);
        qS[c][r][0]  = sb[c * HW_ + gr * W_];
        qS[c][r][65] = sb[c * HW_ + gr * W_ + 63];
    }
    if (tid < W_) qnS[tid] = qn_g[n * HW_ + yq * W_ + tid];

    unsigned long long best[4] = {~0ull, ~0ull, ~0ull, ~0ull};

    for (int ytl = 0; ytl < TILES_PER_SPLIT_V; ++ytl) {
        const int yt = split * TILES_PER_SPLIT_V + ytl;
        __syncthreads();
        #pragma unroll
        for (int k = 0; k < 6; ++k) {
            const int id = tid + k * 256;
            const int sg = id & 15;
            const int c  = (id >> 4) & 15;
            const int r  = id >> 8;
            const int gr = iclamp(4 * yt + r - 1, 0, H_ - 1);
            const float4 v = *(const float4*)&tb[c * HW_ + gr * W_ + sg * 4];
            float* dst = &tS[c][r][1 + sg * 4];
            dst[0] = v.x; dst[1] = v.y; dst[2] = v.z; dst[3] = v.w;
        }
        if (tid < 96) {
            const int c  = tid & 15;
            const int r  = tid >> 4;
            const int gr = iclamp(4 * yt + r - 1, 0, H_ - 1);
            tS[c][r][0]  = tb[c * HW_ + gr * W_];
            tS[c][r][65] = tb[c * HW_ + gr * W_ + 63];
        }
        __syncthreads();

        float acc[4][16];
        #pragma unroll
        for (int a = 0; a < 4; ++a)
            #pragma unroll
            for (int b = 0; b < 16; ++b) acc[a][b] = 0.f;

        for (int c = 0; c < C_; ++c) {
            #pragma unroll
            for (int dy = 0; dy < 3; ++dy) {
                float qv[6], tv[18];
                *(float4*)&qv[0] = *(const float4*)&qS[c][dy][i0];
                *(float2*)&qv[4] = *(const float2*)&qS[c][dy][i0 + 4];
                const float* trow = &tS[c][jrow + dy][jx0];
                *(float4*)&tv[0]  = *(const float4*)&trow[0];
                *(float4*)&tv[4]  = *(const float4*)&trow[4];
                *(float4*)&tv[8]  = *(const float4*)&trow[8];
                *(float4*)&tv[12] = *(const float4*)&trow[12];
                *(float2*)&tv[16] = *(const float2*)&trow[16];
                #pragma unroll
                for (int dx = 0; dx < 3; ++dx)
                    #pragma unroll
                    for (int a = 0; a < 4; ++a)
                        #pragma unroll
                        for (int b = 0; b < 16; ++b)
                            acc[a][b] += qv[a + dx] * tv[b + dx];
            }
        }

        const int jbase = yt * 256 + jrow * W_ + jx0;
        float pnv[16];
        const float* png = &pn_g[n * HW_ + jbase];
        *(float4*)&pnv[0]  = *(const float4*)&png[0];
        *(float4*)&pnv[4]  = *(const float4*)&png[4];
        *(float4*)&pnv[8]  = *(const float4*)&png[8];
        *(float4*)&pnv[12] = *(const float4*)&png[12];
        #pragma unroll
        for (int a = 0; a < 4; ++a) {
            const float qn = qnS[i0 + a];
            #pragma unroll
            for (int b = 0; b < 16; ++b) {
                const float d2 = qn + pnv[b] - 2.f * acc[a][b];
                unsigned long long cand =
                    ((unsigned long long)__float_as_uint(d2) << 32) |
                    (unsigned)(jbase + b);
                best[a] = cand < best[a] ? cand : best[a];
            }
        }
    }

    #pragma unroll
    for (int a = 0; a < 4; ++a) {
        unsigned long long v = best[a];
        #pragma unroll
        for (int mm = 8; mm >= 1; mm >>= 1) {
            unsigned long long o = __shfl_xor(v, mm, 64);
            v = o < v ? o : v;
        }
        best[a] = v;
    }
    if (tx == 0) {
        #pragma unroll
        for (int a = 0; a < 4; ++a)
            partial[((split * N_ + n) * HW_) + yq * W_ + i0 + a] = best[a];
    }
}

__global__ __launch_bounds__(256)
void finalize_kernel(const unsigned long long* __restrict__ partial,
                     float* __restrict__ out) {
    const int id  = blockIdx.x * 256 + threadIdx.x;
    const int n   = id >> 12;
    const int pix = id & 4095;
    unsigned long long best = ~0ull;
    #pragma unroll
    for (int sp = 0; sp < SPLITS_V; ++sp) {
        unsigned long long v = partial[(sp * N_ + n) * HW_ + pix];
        best = v < best ? v : best;
    }
    const unsigned j = (unsigned)(best & 0xffffffffu);
    const float d2 = __uint_as_float((unsigned)(best >> 32));
    out[n * 2 * HW_ + pix]            = (float)(j >> 6);
    out[n * 2 * HW_ + HW_ + pix]      = (float)(j & 63);
    out[N_ * 2 * HW_ + n * HW_ + pix] = d2;
}

__global__ __launch_bounds__(256)
void patchmatch_mono_kernel(const float* __restrict__ s,
                            const float* __restrict__ t,
                            float* __restrict__ out) {
    const int yq  = blockIdx.x;
    const int n   = blockIdx.y;
    const int tid = threadIdx.x;
    const int tx  = tid & 15;
    const int ty  = tid >> 4;
    const int i0  = ty * 4;
    const int jrow = tx >> 3;
    const int jx0  = (tx & 7) * 8;

    __shared__ float qS[C_][3][68];
    __shared__ float tS[C_][4][68];
    __shared__ float pnS[HW_];
    __shared__ float qnS[W_];

    const float* sb = s + n * (C_ * HW_);
    const float* tb = t + n * (C_ * HW_);

    for (int jj = tid; jj < HW_; jj += 256) {
        const int y = jj >> 6, x = jj & 63;
        float acc = 0.f;
        for (int c = 0; c < C_; ++c) {
            const float* tc = tb + c * HW_;
            #pragma unroll
            for (int dy = 0; dy < 3; ++dy) {
                const float* tr = tc + iclamp(y + dy - 1, 0, H_ - 1) * W_;
                #pragma unroll
                for (int dx = 0; dx < 3; ++dx) {
                    float v = tr[iclamp(x + dx - 1, 0, W_ - 1)];
                    acc += v * v;
                }
            }
        }
        pnS[jj] = acc;
    }
    for (int idx = tid; idx < C_ * 3 * 66; idx += 256) {
        const int c   = idx / (3 * 66);
        const int rem = idx - c * (3 * 66);
        const int rr  = rem / 66;
        const int xi  = rem - rr * 66;
        qS[c][rr][xi] = sb[c * HW_ + iclamp(yq + rr - 1, 0, H_ - 1) * W_ +
                           iclamp(xi - 1, 0, W_ - 1)];
    }
    __syncthreads();
    if (tid < W_) {
        float acc = 0.f;
        for (int c = 0; c < C_; ++c)
            #pragma unroll
            for (int dy = 0; dy < 3; ++dy)
                #pragma unroll
                for (int dx = 0; dx < 3; ++dx) {
                    float v = qS[c][dy][tid + dx];
                    acc += v * v;
                }
        qnS[tid] = acc;
    }

    unsigned long long best[4] = {~0ull, ~0ull, ~0ull, ~0ull};
    for (int yt = 0; yt < 32; ++yt) {
        __syncthreads();
        for (int idx = tid; idx < C_ * 4 * 66; idx += 256) {
            const int c   = idx / (4 * 66);
            const int rem = idx - c * (4 * 66);
            const int rr  = rem / 66;
            const int xi  = rem - rr * 66;
            tS[c][rr][xi] = tb[c * HW_ + iclamp(2 * yt + rr - 1, 0, H_ - 1) * W_ +
                               iclamp(xi - 1, 0, W_ - 1)];
        }
        __syncthreads();

        float acc[4][8];
        #pragma unroll
        for (int a = 0; a < 4; ++a)
            #pragma unroll
            for (int b = 0; b < 8; ++b) acc[a][b] = 0.f;

        for (int c = 0; c < C_; ++c) {
            #pragma unroll
            for (int dy = 0; dy < 3; ++dy) {
                float qv[8], tv[12];
                *(float4*)&qv[0] = *(const float4*)&qS[c][dy][i0];
                *(float4*)&qv[4] = *(const float4*)&qS[c][dy][i0 + 4];
                const float* trow = &tS[c][jrow + dy][jx0];
                *(float4*)&tv[0] = *(const float4*)&trow[0];
                *(float4*)&tv[4] = *(const float4*)&trow[4];
                *(float4*)&tv[8] = *(const float4*)&trow[8];
                #pragma unroll
                for (int dx = 0; dx < 3; ++dx)
                    #pragma unroll
                    for (int a = 0; a < 4; ++a)
                        #pragma unroll
                        for (int b = 0; b < 8; ++b)
                            acc[a][b] += qv[a + dx] * tv[b + dx];
            }
        }
        const int rbase = (2 * yt + jrow) * W_ + jx0;
        #pragma unroll
        for (int a = 0; a < 4; ++a) {
            const float qn = qnS[i0 + a];
            #pragma unroll
            for (int b = 0; b < 8; ++b) {
                const int j = rbase + b;
                const float d2 = qn + pnS[j] - 2.f * acc[a][b];
                unsigned long long cand =
                    ((unsigned long long)__float_as_uint(d2) << 32) | (unsigned)j;
                best[a] = cand < best[a] ? cand : best[a];
            }
        }
    }
    #pragma unroll
    for (int a = 0; a < 4; ++a) {
        unsigned long long v = best[a];
        #pragma unroll
        for (int mm = 8; mm >= 1; mm >>= 1) {
            unsigned long long o = __shfl_xor(v, mm, 64);
            v = o < v ? o : v;
        }
        best[a] = v;
    }
    if (tx == 0) {
        #pragma unroll
        for (int a = 0; a < 4; ++a) {
            const int x = i0 + a;
            const unsigned j = (unsigned)(best[a] & 0xffffffffu);
            const float d2 = __uint_as_float((unsigned)(best[a] >> 32));
            const int pix = yq * W_ + x;
            out[n * 2 * HW_ + pix]            = (float)(j >> 6);
            out[n * 2 * HW_ + HW_ + pix]      = (float)(j & 63);
            out[N_ * 2 * HW_ + n * HW_ + pix] = d2;
        }
    }
}

// ===========================================================================
extern "C" void kernel_launch(void* const* d_in, const int* in_sizes, int n_in,
                              void* d_out, int out_size, void* d_ws, size_t ws_size,
                              hipStream_t stream) {
    const float* s = (const float*)d_in[0];
    const float* t = (const float*)d_in[1];
    float* out = (float*)d_out;

    // MFMA ws layout:
    //   pn [4][4096] f32 | qn [4][4096] f32 | partial [4][4][4096] u64 |
    //   Qh | Ql | Ph | Pl   each K-major [4][18][4096][8] f16 (4.72 MB)
    const size_t norm_b  = (size_t)N_ * HW_ * 4;
    const size_t part_b  = (size_t)SPLITS_M * N_ * HW_ * 8;
    const size_t desc_b  = (size_t)N_ * HW_ * KK_ * 8 * 2;
    const size_t need_m  = 2 * norm_b + part_b + 4 * desc_b;     // ~19.5 MB

    if (ws_size >= need_m) {
        char* w = (char*)d_ws;
        float* pn = (float*)w;                       w += norm_b;
        float* qn = (float*)w;                       w += norm_b;
        unsigned long long* partial = (unsigned long long*)w; w += part_b;
        f16* Qh = (f16*)w;  w += desc_b;
        f16* Ql = (f16*)w;  w += desc_b;
        f16* Ph = (f16*)w;  w += desc_b;
        f16* Pl = (f16*)w;

        build_desc_norms_kernel<<<dim3(64, N_, 2), 256, 0, stream>>>(
            s, t, Qh, Ql, Ph, Pl, pn, qn);
        mfma_nn_kernel<<<512, 256, 0, stream>>>(Qh, Ql, Ph, Pl, pn, partial);
        finalize_mfma_kernel<<<64, 256, 0, stream>>>(partial, qn, out);
        return;
    }

    // Fallback: fp32 vector path
    const size_t need_v = 2 * norm_b + (size_t)SPLITS_V * N_ * HW_ * 8;
    if (ws_size >= need_v) {
        float* pn = (float*)d_ws;
        float* qn = pn + N_ * HW_;
        unsigned long long* partial =
            (unsigned long long*)((char*)d_ws + 2 * norm_b);
        prep_norms_kernel<<<128, 256, 0, stream>>>(s, t, pn, qn);
        dim3 grid(H_, N_, SPLITS_V);
        patchmatch_main_kernel<<<grid, 256, 0, stream>>>(s, t, pn, qn, partial);
        finalize_kernel<<<64, 256, 0, stream>>>(partial, out);
        return;
    }

    dim3 grid(H_, N_);
    patchmatch_mono_kernel<<<grid, 256, 0, stream>>>(s, t, out);
}